// Round 1
// baseline (1442.093 us; speedup 1.0000x reference)
//
#include <hip/hip_runtime.h>
#include <hip/hip_bf16.h>
#include <math.h>

#define HC 512
#define NHEAD 4
#define CPH 128
#define NEG_SLOPE 0.2f
#define EPS_BN 1e-5f

// ---------------------------------------------------------------------------
// CSR build: histogram -> scan -> scatter.  Built once per launch, reused by
// all 4 GAT layers (src/dst identical each layer).  Self-loops are edge ids
// j in [E, E+N) with src=dst=j-E.
// ---------------------------------------------------------------------------
__global__ void hist_kernel(const int* __restrict__ dstE, int* __restrict__ cnt,
                            int E, int N) {
    int i = blockIdx.x * 256 + threadIdx.x;
    if (i < E + N) {
        int d = (i < E) ? dstE[i] : (i - E);
        atomicAdd(&cnt[d], 1);
    }
}

__global__ __launch_bounds__(1024) void scan_kernel(int* __restrict__ rowptr,
                                                    int* __restrict__ wr, int n) {
    __shared__ int sm[1024];
    __shared__ int carry;
    int t = threadIdx.x;
    if (t == 0) carry = 0;
    __syncthreads();
    for (int base = 0; base < n; base += 1024) {
        int v = (base + t < n) ? rowptr[base + t] : 0;
        sm[t] = v;
        __syncthreads();
        for (int off = 1; off < 1024; off <<= 1) {
            int add = (t >= off) ? sm[t - off] : 0;
            __syncthreads();
            sm[t] += add;
            __syncthreads();
        }
        int total = sm[1023];
        int excl = sm[t] - v + carry;
        if (base + t < n) { rowptr[base + t] = excl; wr[base + t] = excl; }
        __syncthreads();
        if (t == 0) carry += total;
        __syncthreads();
    }
    if (t == 0) rowptr[n] = carry;
}

__global__ void scatter_kernel(const int* __restrict__ dstE, int* __restrict__ wr,
                               int* __restrict__ eid, int E, int N) {
    int i = blockIdx.x * 256 + threadIdx.x;
    if (i < E + N) {
        int d = (i < E) ? dstE[i] : (i - E);
        int p = atomicAdd(&wr[d], 1);
        eid[p] = i;
    }
}

// ---------------------------------------------------------------------------
// Tiled fp32 GEMM:  C[M,N] = A[M,K] @ B[K,N]   (row-major, K % BK == 0,
// N % BN == 0).  EPI: 0 = none, 1 = +bias then ReLU.
// ---------------------------------------------------------------------------
template <int BM, int BN, int BK, int TM, int TN, int EPI>
__global__ __launch_bounds__(256) void gemm_k(const float* __restrict__ A,
                                              const float* __restrict__ B,
                                              const float* __restrict__ bias,
                                              float* __restrict__ C,
                                              int M, int K, int N) {
    constexpr int PAD = 4;
    __shared__ float sA[BK][BM + PAD];   // transposed: sA[k][row]
    __shared__ float sB[BK][BN];

    const int tid = threadIdx.x;
    const int bm = blockIdx.y * BM, bn = blockIdx.x * BN;
    constexpr int TX = BN / TN;                 // threads along N
    const int tx = tid % TX, ty = tid / TX;

    float acc[TM][TN] = {};

    constexpr int AF4 = BK / 4;                 // float4s per A row
    const int a4 = tid % AF4;
    const int ar0 = tid / AF4;
    constexpr int AROWS = 256 / AF4;
    constexpr int APASS = BM / AROWS;

    constexpr int BF4 = BN / 4;                 // float4s per B row
    const int b4 = tid % BF4;
    const int br0 = tid / BF4;
    constexpr int BROWS = 256 / BF4;
    constexpr int BPASS = BK / BROWS;

    for (int kt = 0; kt < K; kt += BK) {
        __syncthreads();
#pragma unroll
        for (int p = 0; p < APASS; ++p) {
            int row = ar0 + p * AROWS;
            int gr = bm + row;
            if (gr >= M) gr = M - 1;            // clamp; result discarded on store
            float4 v = *(const float4*)&A[(size_t)gr * K + kt + a4 * 4];
            sA[a4 * 4 + 0][row] = v.x;
            sA[a4 * 4 + 1][row] = v.y;
            sA[a4 * 4 + 2][row] = v.z;
            sA[a4 * 4 + 3][row] = v.w;
        }
#pragma unroll
        for (int p = 0; p < BPASS; ++p) {
            int row = br0 + p * BROWS;
            float4 v = *(const float4*)&B[(size_t)(kt + row) * N + bn + b4 * 4];
            *(float4*)&sB[row][b4 * 4] = v;
        }
        __syncthreads();
#pragma unroll
        for (int k = 0; k < BK; ++k) {
            float ar[TM], br[TN];
#pragma unroll
            for (int i = 0; i < TM; i += 4)
                *(float4*)&ar[i] = *(const float4*)&sA[k][ty * TM + i];
#pragma unroll
            for (int j = 0; j < TN; j += 4)
                *(float4*)&br[j] = *(const float4*)&sB[k][tx * TN + j];
#pragma unroll
            for (int i = 0; i < TM; ++i)
#pragma unroll
                for (int j = 0; j < TN; ++j)
                    acc[i][j] = fmaf(ar[i], br[j], acc[i][j]);
        }
    }

#pragma unroll
    for (int i = 0; i < TM; ++i) {
        int r = bm + ty * TM + i;
        if (r >= M) continue;
#pragma unroll
        for (int j = 0; j < TN; j += 4) {
            int c = bn + tx * TN + j;
            float4 v;
            v.x = acc[i][j + 0];
            v.y = acc[i][j + 1];
            v.z = acc[i][j + 2];
            v.w = acc[i][j + 3];
            if (EPI == 1) {
                v.x = fmaxf(v.x + bias[c + 0], 0.f);
                v.y = fmaxf(v.y + bias[c + 1], 0.f);
                v.z = fmaxf(v.z + bias[c + 2], 0.f);
                v.w = fmaxf(v.w + bias[c + 3], 0.f);
            }
            *(float4*)&C[(size_t)r * N + c] = v;
        }
    }
}

// ---------------------------------------------------------------------------
// Per-node attention coefficients: al_s[n][h] = sum_c h[n,h,c]*a_src[h,c]
// One wave per node; lane l owns channels l, l+64, ..., l+448.
// ---------------------------------------------------------------------------
__global__ __launch_bounds__(256) void al_kernel(const float* __restrict__ hbuf,
                                                 const float* __restrict__ asrc,
                                                 const float* __restrict__ adst,
                                                 float* __restrict__ al_s,
                                                 float* __restrict__ al_d, int N) {
    int wid = (blockIdx.x * 256 + threadIdx.x) >> 6;
    int lane = threadIdx.x & 63;
    if (wid >= N) return;
    const float* hp = hbuf + (size_t)wid * HC;
    float ss[NHEAD] = {0, 0, 0, 0}, sd[NHEAD] = {0, 0, 0, 0};
#pragma unroll
    for (int k = 0; k < 8; ++k) {
        int c = lane + 64 * k;
        float v = hp[c];
        ss[k >> 1] = fmaf(v, asrc[c], ss[k >> 1]);
        sd[k >> 1] = fmaf(v, adst[c], sd[k >> 1]);
    }
#pragma unroll
    for (int off = 32; off; off >>= 1) {
#pragma unroll
        for (int h = 0; h < NHEAD; ++h) {
            ss[h] += __shfl_xor(ss[h], off);
            sd[h] += __shfl_xor(sd[h], off);
        }
    }
    float vs = ss[0], vd = sd[0];
    if (lane == 1) { vs = ss[1]; vd = sd[1]; }
    if (lane == 2) { vs = ss[2]; vd = sd[2]; }
    if (lane == 3) { vs = ss[3]; vd = sd[3]; }
    if (lane < NHEAD) {
        al_s[wid * NHEAD + lane] = vs;
        al_d[wid * NHEAD + lane] = vd;
    }
}

// ---------------------------------------------------------------------------
// Aggregation: one wave per dst node.  3 phases over the node's in-edges:
// (1) per-head max of leaky_relu(al_s[src]+al_d[dst]), (2) sum of exp,
// (3) weighted accumulation of h[src] (8 channels per lane).  +bias, ELU.
// ---------------------------------------------------------------------------
__global__ __launch_bounds__(256) void agg_kernel(const float* __restrict__ hbuf,
                                                  const float* __restrict__ al_s,
                                                  const float* __restrict__ al_d,
                                                  const int* __restrict__ rowptr,
                                                  const int* __restrict__ eid,
                                                  const int* __restrict__ srcE,
                                                  const float* __restrict__ bias,
                                                  float* __restrict__ out,
                                                  int N, int E) {
    int node = (blockIdx.x * 256 + threadIdx.x) >> 6;
    int lane = threadIdx.x & 63;
    if (node >= N) return;
    int e0 = rowptr[node], e1 = rowptr[node + 1];
    float4 ald = *(const float4*)&al_d[node * NHEAD];
    float aldv[NHEAD] = {ald.x, ald.y, ald.z, ald.w};

    // phase 1: per-head max
    float m[NHEAD] = {-INFINITY, -INFINITY, -INFINITY, -INFINITY};
    for (int i = e0 + lane; i < e1; i += 64) {
        int j = eid[i];
        int src = (j < E) ? srcE[j] : node;
        float4 als = *(const float4*)&al_s[src * NHEAD];
        float alsv[NHEAD] = {als.x, als.y, als.z, als.w};
#pragma unroll
        for (int h = 0; h < NHEAD; ++h) {
            float e = alsv[h] + aldv[h];
            e = (e > 0.f) ? e : NEG_SLOPE * e;
            m[h] = fmaxf(m[h], e);
        }
    }
#pragma unroll
    for (int off = 32; off; off >>= 1)
#pragma unroll
        for (int h = 0; h < NHEAD; ++h) m[h] = fmaxf(m[h], __shfl_xor(m[h], off));

    // phase 2: sum of exp
    float s[NHEAD] = {0, 0, 0, 0};
    for (int i = e0 + lane; i < e1; i += 64) {
        int j = eid[i];
        int src = (j < E) ? srcE[j] : node;
        float4 als = *(const float4*)&al_s[src * NHEAD];
        float alsv[NHEAD] = {als.x, als.y, als.z, als.w};
#pragma unroll
        for (int h = 0; h < NHEAD; ++h) {
            float e = alsv[h] + aldv[h];
            e = (e > 0.f) ? e : NEG_SLOPE * e;
            s[h] += expf(e - m[h]);
        }
    }
#pragma unroll
    for (int off = 32; off; off >>= 1)
#pragma unroll
        for (int h = 0; h < NHEAD; ++h) s[h] += __shfl_xor(s[h], off);
    float rs[NHEAD];
#pragma unroll
    for (int h = 0; h < NHEAD; ++h) rs[h] = 1.f / (s[h] + 1e-16f);

    // phase 3: weighted gather
    float acc[8] = {0, 0, 0, 0, 0, 0, 0, 0};
    for (int i = e0; i < e1; ++i) {
        int j = eid[i];
        int src = (j < E) ? srcE[j] : node;
        float4 als = *(const float4*)&al_s[src * NHEAD];
        float alsv[NHEAD] = {als.x, als.y, als.z, als.w};
        float a[NHEAD];
#pragma unroll
        for (int h = 0; h < NHEAD; ++h) {
            float e = alsv[h] + aldv[h];
            e = (e > 0.f) ? e : NEG_SLOPE * e;
            a[h] = expf(e - m[h]) * rs[h];
        }
        const float* hp = hbuf + (size_t)src * HC;
#pragma unroll
        for (int k = 0; k < 8; ++k)
            acc[k] = fmaf(hp[lane + 64 * k], a[k >> 1], acc[k]);
    }
#pragma unroll
    for (int k = 0; k < 8; ++k) {
        int c = lane + 64 * k;
        float v = acc[k] + bias[c];
        v = (v > 0.f) ? v : (expf(v) - 1.f);      // ELU
        out[(size_t)node * HC + c] = v;
    }
}

// ---------------------------------------------------------------------------
// BatchNorm: stats (sum / sumsq per channel) then in-place apply.
// ---------------------------------------------------------------------------
__global__ __launch_bounds__(256) void bnstat_kernel(const float* __restrict__ x,
                                                     float* __restrict__ stats, int N) {
    int tid = threadIdx.x;
    float s0 = 0, s1 = 0, q0 = 0, q1 = 0;
    for (int r = blockIdx.x; r < N; r += gridDim.x) {
        float v0 = x[(size_t)r * HC + tid];
        float v1 = x[(size_t)r * HC + 256 + tid];
        s0 += v0; q0 += v0 * v0;
        s1 += v1; q1 += v1 * v1;
    }
    atomicAdd(&stats[tid], s0);
    atomicAdd(&stats[HC + tid], q0);
    atomicAdd(&stats[256 + tid], s1);
    atomicAdd(&stats[HC + 256 + tid], q1);
}

__global__ __launch_bounds__(256) void bnapply_kernel(float* __restrict__ x,
                                                      const float* __restrict__ stats,
                                                      const float* __restrict__ g,
                                                      const float* __restrict__ bt,
                                                      int total, float invN) {
    for (int i = blockIdx.x * 256 + threadIdx.x; i < total; i += gridDim.x * 256) {
        int c = i & (HC - 1);
        float mu = stats[c] * invN;
        float var = stats[HC + c] * invN - mu * mu;
        x[i] = (x[i] - mu) * rsqrtf(var + EPS_BN) * g[c] + bt[c];
    }
}

// ---------------------------------------------------------------------------
// Head: logits = x[N,64] @ w[64,10] + b; out = log_softmax.  One wave per row.
// ---------------------------------------------------------------------------
__global__ __launch_bounds__(256) void head_kernel(const float* __restrict__ x,
                                                   const float* __restrict__ w,
                                                   const float* __restrict__ b,
                                                   float* __restrict__ out, int N) {
    int wid = (blockIdx.x * 256 + threadIdx.x) >> 6;
    int lane = threadIdx.x & 63;
    if (wid >= N) return;
    float v = x[(size_t)wid * 64 + lane];
    float my = -INFINITY;
#pragma unroll
    for (int j = 0; j < 10; ++j) {
        float t = v * w[lane * 10 + j];
#pragma unroll
        for (int off = 32; off; off >>= 1) t += __shfl_xor(t, off);
        t += b[j];
        if (lane == j) my = t;
    }
    float mx = my;
#pragma unroll
    for (int off = 32; off; off >>= 1) mx = fmaxf(mx, __shfl_xor(mx, off));
    float p = (lane < 10) ? expf(my - mx) : 0.f;
    float sum = p;
#pragma unroll
    for (int off = 32; off; off >>= 1) sum += __shfl_xor(sum, off);
    if (lane < 10) out[(size_t)wid * 10 + lane] = my - mx - logf(sum);
}

// ---------------------------------------------------------------------------
extern "C" void kernel_launch(void* const* d_in, const int* in_sizes, int n_in,
                              void* d_out, int out_size, void* d_ws, size_t ws_size,
                              hipStream_t stream) {
    const float* x = (const float*)d_in[0];
    const int* ei = (const int*)d_in[1];        // [2, E] int32
    const int N = in_sizes[0] / 128;
    const int E = in_sizes[1] / 2;
    const int EN = E + N;

    // workspace layout
    float* ws = (float*)d_ws;
    float* bufH = ws;                                   // N*512
    float* bufP = bufH + (size_t)N * HC;                // N*512
    float* bufQ = bufP + (size_t)N * HC;                // N*512
    float* als  = bufQ + (size_t)N * HC;                // N*4
    float* ald  = als + (size_t)N * NHEAD;              // N*4
    float* stats = ald + (size_t)N * NHEAD;             // 1024
    int* rowptr = (int*)(stats + 1024);                 // N+1
    int* wr = rowptr + (N + 1);                         // N
    int* eid = wr + N;                                  // E+N

    // --- CSR build (once; reused by all 4 layers) ---
    hipMemsetAsync(rowptr, 0, (N + 1) * sizeof(int), stream);
    hist_kernel<<<(EN + 255) / 256, 256, 0, stream>>>(ei + E, rowptr, E, N);
    scan_kernel<<<1, 1024, 0, stream>>>(rowptr, wr, N);
    scatter_kernel<<<(EN + 255) / 256, 256, 0, stream>>>(ei + E, wr, eid, E, N);

    const int nodeBlocks = (N * 64 + 255) / 256;
    const float* cur = x;
    int curK = 128;
    float* outs[4] = {bufP, bufQ, bufP, bufQ};

    for (int L = 0; L < 4; ++L) {
        const float* W  = (const float*)d_in[3 + 6 * L];
        const float* as_ = (const float*)d_in[4 + 6 * L];
        const float* ad_ = (const float*)d_in[5 + 6 * L];
        const float* b_  = (const float*)d_in[6 + 6 * L];
        const float* g_  = (const float*)d_in[7 + 6 * L];
        const float* bt_ = (const float*)d_in[8 + 6 * L];

        gemm_k<128, 128, 16, 8, 8, 0><<<dim3(HC / 128, (N + 127) / 128), 256, 0, stream>>>(
            cur, W, nullptr, bufH, N, curK, HC);
        al_kernel<<<nodeBlocks, 256, 0, stream>>>(bufH, as_, ad_, als, ald, N);
        agg_kernel<<<nodeBlocks, 256, 0, stream>>>(bufH, als, ald, rowptr, eid, ei,
                                                   b_, outs[L], N, E);
        hipMemsetAsync(stats, 0, 1024 * sizeof(float), stream);
        bnstat_kernel<<<256, 256, 0, stream>>>(outs[L], stats, N);
        bnapply_kernel<<<2048, 256, 0, stream>>>(outs[L], stats, g_, bt_, N * HC,
                                                 1.f / (float)N);
        cur = outs[L];
        curK = HC;
    }

    // --- MLP head ---
    const float* lw1 = (const float*)d_in[27];
    const float* lb1 = (const float*)d_in[28];
    const float* lw2 = (const float*)d_in[29];
    const float* lb2 = (const float*)d_in[30];
    const float* lw3 = (const float*)d_in[31];
    const float* lb3 = (const float*)d_in[32];

    float* m1 = bufH;                        // N*128 (bufH free now)
    float* m2 = bufH + (size_t)N * 128;      // N*64

    gemm_k<64, 64, 16, 4, 4, 1><<<dim3(128 / 64, (N + 63) / 64), 256, 0, stream>>>(
        cur, lw1, lb1, m1, N, HC, 128);
    gemm_k<64, 64, 16, 4, 4, 1><<<dim3(1, (N + 63) / 64), 256, 0, stream>>>(
        m1, lw2, lb2, m2, N, 128, 64);
    head_kernel<<<nodeBlocks, 256, 0, stream>>>(m2, lw3, lb3, (float*)d_out, N);
}

// Round 2
// 1143.464 us; speedup vs baseline: 1.2612x; 1.2612x over previous
//
#include <hip/hip_runtime.h>
#include <hip/hip_bf16.h>
#include <math.h>

#define HC 512
#define NHEAD 4
#define NEG_SLOPE 0.2f
#define EPS_BN 1e-5f

typedef __attribute__((ext_vector_type(8))) short short8v;   // 8 bf16 = 4 VGPRs
typedef __attribute__((ext_vector_type(4))) float f32x4;

#define GLOAD16(gptr, lptr)                                                      \
    __builtin_amdgcn_global_load_lds(                                            \
        (const __attribute__((address_space(1))) unsigned int*)(gptr),           \
        (__attribute__((address_space(3))) unsigned int*)(lptr), 16, 0, 0)

// ---------------------------------------------------------------------------
// CSR build: histogram -> scan -> scatter.  Built once per launch, reused by
// all 4 GAT layers.  Self-loop edge ids j in [E, E+N) have src=dst=j-E.
// ---------------------------------------------------------------------------
__global__ void hist_kernel(const int* __restrict__ dstE, int* __restrict__ cnt,
                            int E, int N) {
    int i = blockIdx.x * 256 + threadIdx.x;
    if (i < E + N) {
        int d = (i < E) ? dstE[i] : (i - E);
        atomicAdd(&cnt[d], 1);
    }
}

__global__ __launch_bounds__(1024) void scan_kernel(int* __restrict__ rowptr,
                                                    int* __restrict__ wr, int n) {
    __shared__ int sm[1024];
    __shared__ int carry;
    int t = threadIdx.x;
    if (t == 0) carry = 0;
    __syncthreads();
    for (int base = 0; base < n; base += 1024) {
        int v = (base + t < n) ? rowptr[base + t] : 0;
        sm[t] = v;
        __syncthreads();
        for (int off = 1; off < 1024; off <<= 1) {
            int add = (t >= off) ? sm[t - off] : 0;
            __syncthreads();
            sm[t] += add;
            __syncthreads();
        }
        int total = sm[1023];
        int excl = sm[t] - v + carry;
        if (base + t < n) { rowptr[base + t] = excl; wr[base + t] = excl; }
        __syncthreads();
        if (t == 0) carry += total;
        __syncthreads();
    }
    if (t == 0) rowptr[n] = carry;
}

__global__ void scatter_kernel(const int* __restrict__ dstE, int* __restrict__ wr,
                               int* __restrict__ eid, int E, int N) {
    int i = blockIdx.x * 256 + threadIdx.x;
    if (i < E + N) {
        int d = (i < E) ? dstE[i] : (i - E);
        int p = atomicAdd(&wr[d], 1);
        eid[p] = i;
    }
}

// ---------------------------------------------------------------------------
// Weight transpose + hi/lo bf16 split:  W fp32 [K][Nc] -> WT{hi,lo} [Nc][K].
// ---------------------------------------------------------------------------
__global__ __launch_bounds__(256) void wsplit_kernel(const float* __restrict__ W,
                                                     __hip_bfloat16* __restrict__ hiT,
                                                     __hip_bfloat16* __restrict__ loT,
                                                     int K, int Nc) {
    __shared__ float tile[32][33];
    int bx = blockIdx.x * 32;   // n
    int by = blockIdx.y * 32;   // k
    int tx = threadIdx.x & 31, ty = threadIdx.x >> 5;   // 32 x 8
#pragma unroll
    for (int r = 0; r < 32; r += 8)
        tile[ty + r][tx] = W[(size_t)(by + ty + r) * Nc + bx + tx];
    __syncthreads();
#pragma unroll
    for (int r = 0; r < 32; r += 8) {
        float v = tile[tx][ty + r];                    // = W[by+tx][bx+ty+r]... careful below
        // out[n][k] with n = bx + (ty+r)?  Re-derive: we want coalesced writes along k.
        // write index: n = bx + (ty + r)?? -- use: n varies with ty+r, k varies with tx
        int n = bx + ty + r;
        int k = by + tx;
        float w = tile[tx][ty + r];                    // tile[kk][nn] = W[by+kk][bx+nn] -> kk=tx, nn=ty+r
        __hip_bfloat16 h = __float2bfloat16(w);
        float hf = __bfloat162float(h);
        hiT[(size_t)n * K + k] = h;
        loT[(size_t)n * K + k] = __float2bfloat16(w - hf);
        (void)v; (void)n; (void)k;
    }
}

// ---------------------------------------------------------------------------
// Elementwise hi/lo split (layer-1 input x).
// ---------------------------------------------------------------------------
__global__ __launch_bounds__(256) void xsplit_kernel(const float* __restrict__ x,
                                                     __hip_bfloat16* __restrict__ hi,
                                                     __hip_bfloat16* __restrict__ lo,
                                                     int total) {
    for (int i = blockIdx.x * 256 + threadIdx.x; i < total; i += gridDim.x * 256) {
        float v = x[i];
        __hip_bfloat16 h = __float2bfloat16(v);
        hi[i] = h;
        lo[i] = __float2bfloat16(v - __bfloat162float(h));
    }
}

// ---------------------------------------------------------------------------
// bf16 split-GEMM:  C[M,Nc] = (Ahi+Alo)[M,K] @ (Bhi+Blo)[K,Nc], B given as B^T
// [Nc][K].  128x128 tile, BK=32, 4 waves (2x2), 16x16x32 MFMA, 3 products
// (hi*hi + hi*lo + lo*hi).  global_load_lds width-16 staging (m97 structure).
// ---------------------------------------------------------------------------
__global__ __launch_bounds__(256) void mfma_gemm(const __hip_bfloat16* __restrict__ Ahi,
                                                 const __hip_bfloat16* __restrict__ Alo,
                                                 const __hip_bfloat16* __restrict__ BThi,
                                                 const __hip_bfloat16* __restrict__ BTlo,
                                                 float* __restrict__ C,
                                                 int M, int K, int Nc) {
    __shared__ short sm[4 * 128 * 32];          // 32 KiB: Ahi | Alo | Bhi | Blo
    short* sAhi = sm;
    short* sAlo = sm + 4096;
    short* sBhi = sm + 8192;
    short* sBlo = sm + 12288;

    const int tid = threadIdx.x;
    const int wid = tid >> 6, lane = tid & 63;
    const int wm = wid >> 1, wn = wid & 1;      // wave grid 2x2, each 64x64
    const int bm = blockIdx.y * 128, bn = blockIdx.x * 128;

    // staging geometry: chunk c covers rows [c*16, c*16+16), lane l -> row c*16+l/4,
    // col elems (l&3)*8.  Wave w stages chunks {2w, 2w+1} of each tile.
    const int rowl = lane >> 2;
    const int cole = (lane & 3) * 8;
    const int c0 = wid * 2;

    // fragment geometry
    const int frow = lane & 15;
    const int fko = (lane >> 4) * 8;

    f32x4 acc[4][4] = {};

    for (int k0 = 0; k0 < K; k0 += 32) {
#pragma unroll
        for (int cc = 0; cc < 2; ++cc) {
            int c = c0 + cc;
            int ra = bm + c * 16 + rowl; if (ra >= M) ra = M - 1;
            int rb = bn + c * 16 + rowl;
            const __hip_bfloat16* ga_hi = Ahi + (size_t)ra * K + k0 + cole;
            const __hip_bfloat16* ga_lo = Alo + (size_t)ra * K + k0 + cole;
            const __hip_bfloat16* gb_hi = BThi + (size_t)rb * K + k0 + cole;
            const __hip_bfloat16* gb_lo = BTlo + (size_t)rb * K + k0 + cole;
            GLOAD16(ga_hi, &sAhi[c * 512]);
            GLOAD16(ga_lo, &sAlo[c * 512]);
            GLOAD16(gb_hi, &sBhi[c * 512]);
            GLOAD16(gb_lo, &sBlo[c * 512]);
        }
        __syncthreads();

        short8v ah[4], al_[4], bh[4], bl[4];
#pragma unroll
        for (int mi = 0; mi < 4; ++mi) {
            int r = wm * 64 + mi * 16 + frow;
            ah[mi] = *(const short8v*)&sAhi[r * 32 + fko];
            al_[mi] = *(const short8v*)&sAlo[r * 32 + fko];
        }
#pragma unroll
        for (int ni = 0; ni < 4; ++ni) {
            int r = wn * 64 + ni * 16 + frow;
            bh[ni] = *(const short8v*)&sBhi[r * 32 + fko];
            bl[ni] = *(const short8v*)&sBlo[r * 32 + fko];
        }
#pragma unroll
        for (int mi = 0; mi < 4; ++mi)
#pragma unroll
            for (int ni = 0; ni < 4; ++ni) {
                acc[mi][ni] = __builtin_amdgcn_mfma_f32_16x16x32_bf16(ah[mi], bh[ni], acc[mi][ni], 0, 0, 0);
                acc[mi][ni] = __builtin_amdgcn_mfma_f32_16x16x32_bf16(ah[mi], bl[ni], acc[mi][ni], 0, 0, 0);
                acc[mi][ni] = __builtin_amdgcn_mfma_f32_16x16x32_bf16(al_[mi], bh[ni], acc[mi][ni], 0, 0, 0);
            }
        __syncthreads();
    }

    // C/D layout: col = lane&15, row = (lane>>4)*4 + reg   [m89-verified]
    const int crow = (lane >> 4) * 4;
    const int ccol = lane & 15;
#pragma unroll
    for (int mi = 0; mi < 4; ++mi)
#pragma unroll
        for (int ni = 0; ni < 4; ++ni) {
            int gc = bn + wn * 64 + ni * 16 + ccol;
#pragma unroll
            for (int r = 0; r < 4; ++r) {
                int gr = bm + wm * 64 + mi * 16 + crow + r;
                if (gr < M) C[(size_t)gr * Nc + gc] = acc[mi][ni][r];
            }
        }
}

// ---------------------------------------------------------------------------
// Tiled fp32 GEMM (kept for the small MLP layers).  EPI: 1 = +bias, ReLU.
// ---------------------------------------------------------------------------
template <int BM, int BN, int BK, int TM, int TN, int EPI>
__global__ __launch_bounds__(256) void gemm_k(const float* __restrict__ A,
                                              const float* __restrict__ B,
                                              const float* __restrict__ bias,
                                              float* __restrict__ C,
                                              int M, int K, int N) {
    constexpr int PAD = 4;
    __shared__ float sA[BK][BM + PAD];
    __shared__ float sB[BK][BN];

    const int tid = threadIdx.x;
    const int bm = blockIdx.y * BM, bn = blockIdx.x * BN;
    constexpr int TX = BN / TN;
    const int tx = tid % TX, ty = tid / TX;

    float acc[TM][TN] = {};

    constexpr int AF4 = BK / 4;
    const int a4 = tid % AF4;
    const int ar0 = tid / AF4;
    constexpr int AROWS = 256 / AF4;
    constexpr int APASS = BM / AROWS;

    constexpr int BF4 = BN / 4;
    const int b4 = tid % BF4;
    const int br0 = tid / BF4;
    constexpr int BROWS = 256 / BF4;
    constexpr int BPASS = BK / BROWS;

    for (int kt = 0; kt < K; kt += BK) {
        __syncthreads();
#pragma unroll
        for (int p = 0; p < APASS; ++p) {
            int row = ar0 + p * AROWS;
            int gr = bm + row;
            if (gr >= M) gr = M - 1;
            float4 v = *(const float4*)&A[(size_t)gr * K + kt + a4 * 4];
            sA[a4 * 4 + 0][row] = v.x;
            sA[a4 * 4 + 1][row] = v.y;
            sA[a4 * 4 + 2][row] = v.z;
            sA[a4 * 4 + 3][row] = v.w;
        }
#pragma unroll
        for (int p = 0; p < BPASS; ++p) {
            int row = br0 + p * BROWS;
            float4 v = *(const float4*)&B[(size_t)(kt + row) * N + bn + b4 * 4];
            *(float4*)&sB[row][b4 * 4] = v;
        }
        __syncthreads();
#pragma unroll
        for (int k = 0; k < BK; ++k) {
            float ar[TM], br[TN];
#pragma unroll
            for (int i = 0; i < TM; i += 4)
                *(float4*)&ar[i] = *(const float4*)&sA[k][ty * TM + i];
#pragma unroll
            for (int j = 0; j < TN; j += 4)
                *(float4*)&br[j] = *(const float4*)&sB[k][tx * TN + j];
#pragma unroll
            for (int i = 0; i < TM; ++i)
#pragma unroll
                for (int j = 0; j < TN; ++j)
                    acc[i][j] = fmaf(ar[i], br[j], acc[i][j]);
        }
    }

#pragma unroll
    for (int i = 0; i < TM; ++i) {
        int r = bm + ty * TM + i;
        if (r >= M) continue;
#pragma unroll
        for (int j = 0; j < TN; j += 4) {
            int c = bn + tx * TN + j;
            float4 v;
            v.x = acc[i][j + 0]; v.y = acc[i][j + 1];
            v.z = acc[i][j + 2]; v.w = acc[i][j + 3];
            if (EPI == 1) {
                v.x = fmaxf(v.x + bias[c + 0], 0.f);
                v.y = fmaxf(v.y + bias[c + 1], 0.f);
                v.z = fmaxf(v.z + bias[c + 2], 0.f);
                v.w = fmaxf(v.w + bias[c + 3], 0.f);
            }
            *(float4*)&C[(size_t)r * N + c] = v;
        }
    }
}

// ---------------------------------------------------------------------------
// Per-node attention coefficients (one wave per node).
// ---------------------------------------------------------------------------
__global__ __launch_bounds__(256) void al_kernel(const float* __restrict__ hbuf,
                                                 const float* __restrict__ asrc,
                                                 const float* __restrict__ adst,
                                                 float* __restrict__ al_s,
                                                 float* __restrict__ al_d, int N) {
    int wid = (blockIdx.x * 256 + threadIdx.x) >> 6;
    int lane = threadIdx.x & 63;
    if (wid >= N) return;
    const float* hp = hbuf + (size_t)wid * HC;
    float ss[NHEAD] = {0, 0, 0, 0}, sd[NHEAD] = {0, 0, 0, 0};
#pragma unroll
    for (int k = 0; k < 8; ++k) {
        int c = lane + 64 * k;
        float v = hp[c];
        ss[k >> 1] = fmaf(v, asrc[c], ss[k >> 1]);
        sd[k >> 1] = fmaf(v, adst[c], sd[k >> 1]);
    }
#pragma unroll
    for (int off = 32; off; off >>= 1) {
#pragma unroll
        for (int h = 0; h < NHEAD; ++h) {
            ss[h] += __shfl_xor(ss[h], off);
            sd[h] += __shfl_xor(sd[h], off);
        }
    }
    float vs = ss[0], vd = sd[0];
    if (lane == 1) { vs = ss[1]; vd = sd[1]; }
    if (lane == 2) { vs = ss[2]; vd = sd[2]; }
    if (lane == 3) { vs = ss[3]; vd = sd[3]; }
    if (lane < NHEAD) {
        al_s[wid * NHEAD + lane] = vs;
        al_d[wid * NHEAD + lane] = vd;
    }
}

// ---------------------------------------------------------------------------
// Aggregation: one wave per dst node.  Phases: per-head max -> sum of exp ->
// float4-vectorized weighted gather.  +bias, ELU.
// ---------------------------------------------------------------------------
__global__ __launch_bounds__(256) void agg_kernel(const float* __restrict__ hbuf,
                                                  const float* __restrict__ al_s,
                                                  const float* __restrict__ al_d,
                                                  const int* __restrict__ rowptr,
                                                  const int* __restrict__ eid,
                                                  const int* __restrict__ srcE,
                                                  const float* __restrict__ bias,
                                                  float* __restrict__ out,
                                                  int N, int E) {
    int node = (blockIdx.x * 256 + threadIdx.x) >> 6;
    int lane = threadIdx.x & 63;
    if (node >= N) return;
    int e0 = rowptr[node], e1 = rowptr[node + 1];
    float4 ald = *(const float4*)&al_d[node * NHEAD];
    float aldv[NHEAD] = {ald.x, ald.y, ald.z, ald.w};

    // phase 1: per-head max of leaky_relu logits
    float m[NHEAD] = {-INFINITY, -INFINITY, -INFINITY, -INFINITY};
    for (int i = e0 + lane; i < e1; i += 64) {
        int j = eid[i];
        int src = (j < E) ? srcE[j] : node;
        float4 als = *(const float4*)&al_s[src * NHEAD];
        float alsv[NHEAD] = {als.x, als.y, als.z, als.w};
#pragma unroll
        for (int h = 0; h < NHEAD; ++h) {
            float e = alsv[h] + aldv[h];
            e = (e > 0.f) ? e : NEG_SLOPE * e;
            m[h] = fmaxf(m[h], e);
        }
    }
#pragma unroll
    for (int off = 32; off; off >>= 1)
#pragma unroll
        for (int h = 0; h < NHEAD; ++h) m[h] = fmaxf(m[h], __shfl_xor(m[h], off));

    // phase 2: sum of exp
    float s[NHEAD] = {0, 0, 0, 0};
    for (int i = e0 + lane; i < e1; i += 64) {
        int j = eid[i];
        int src = (j < E) ? srcE[j] : node;
        float4 als = *(const float4*)&al_s[src * NHEAD];
        float alsv[NHEAD] = {als.x, als.y, als.z, als.w};
#pragma unroll
        for (int h = 0; h < NHEAD; ++h) {
            float e = alsv[h] + aldv[h];
            e = (e > 0.f) ? e : NEG_SLOPE * e;
            s[h] += __expf(e - m[h]);
        }
    }
#pragma unroll
    for (int off = 32; off; off >>= 1)
#pragma unroll
        for (int h = 0; h < NHEAD; ++h) s[h] += __shfl_xor(s[h], off);

    // lane's two heads: channels 4*lane..+3 (head h0) and 256+4*lane..+3 (head h0+2)
    bool hi2 = (lane & 32) != 0;
    float m0 = hi2 ? m[1] : m[0], m1 = hi2 ? m[3] : m[2];
    float r0 = 1.f / ((hi2 ? s[1] : s[0]) + 1e-16f);
    float r1 = 1.f / ((hi2 ? s[3] : s[2]) + 1e-16f);
    float ad0 = hi2 ? aldv[1] : aldv[0];
    float ad1 = hi2 ? aldv[3] : aldv[2];

    // phase 3: weighted float4 gather
    float4 acc0 = {0, 0, 0, 0}, acc1 = {0, 0, 0, 0};
    for (int i = e0; i < e1; ++i) {
        int j = eid[i];
        int src = (j < E) ? srcE[j] : node;
        float4 als = *(const float4*)&al_s[src * NHEAD];
        float as0 = hi2 ? als.y : als.x;
        float as1 = hi2 ? als.w : als.z;
        float e0f = as0 + ad0; e0f = (e0f > 0.f) ? e0f : NEG_SLOPE * e0f;
        float e1f = as1 + ad1; e1f = (e1f > 0.f) ? e1f : NEG_SLOPE * e1f;
        float w0 = __expf(e0f - m0) * r0;
        float w1 = __expf(e1f - m1) * r1;
        const float4* hp4 = (const float4*)(hbuf + (size_t)src * HC);
        float4 v0 = hp4[lane];
        float4 v1 = hp4[64 + lane];
        acc0.x = fmaf(v0.x, w0, acc0.x); acc0.y = fmaf(v0.y, w0, acc0.y);
        acc0.z = fmaf(v0.z, w0, acc0.z); acc0.w = fmaf(v0.w, w0, acc0.w);
        acc1.x = fmaf(v1.x, w1, acc1.x); acc1.y = fmaf(v1.y, w1, acc1.y);
        acc1.z = fmaf(v1.z, w1, acc1.z); acc1.w = fmaf(v1.w, w1, acc1.w);
    }

    const float4* b4 = (const float4*)bias;
    float4 bb0 = b4[lane], bb1 = b4[64 + lane];
    float4 o0, o1;
    o0.x = acc0.x + bb0.x; o0.y = acc0.y + bb0.y; o0.z = acc0.z + bb0.z; o0.w = acc0.w + bb0.w;
    o1.x = acc1.x + bb1.x; o1.y = acc1.y + bb1.y; o1.z = acc1.z + bb1.z; o1.w = acc1.w + bb1.w;
    o0.x = (o0.x > 0.f) ? o0.x : (__expf(o0.x) - 1.f);
    o0.y = (o0.y > 0.f) ? o0.y : (__expf(o0.y) - 1.f);
    o0.z = (o0.z > 0.f) ? o0.z : (__expf(o0.z) - 1.f);
    o0.w = (o0.w > 0.f) ? o0.w : (__expf(o0.w) - 1.f);
    o1.x = (o1.x > 0.f) ? o1.x : (__expf(o1.x) - 1.f);
    o1.y = (o1.y > 0.f) ? o1.y : (__expf(o1.y) - 1.f);
    o1.z = (o1.z > 0.f) ? o1.z : (__expf(o1.z) - 1.f);
    o1.w = (o1.w > 0.f) ? o1.w : (__expf(o1.w) - 1.f);
    float4* op = (float4*)(out + (size_t)node * HC);
    op[lane] = o0;
    op[64 + lane] = o1;
}

// ---------------------------------------------------------------------------
// BatchNorm stats + apply (apply also emits hi/lo bf16 split for next GEMM).
// ---------------------------------------------------------------------------
__global__ __launch_bounds__(256) void bnstat_kernel(const float* __restrict__ x,
                                                     float* __restrict__ stats, int N) {
    int tid = threadIdx.x;
    float s0 = 0, s1 = 0, q0 = 0, q1 = 0;
    for (int r = blockIdx.x; r < N; r += gridDim.x) {
        float v0 = x[(size_t)r * HC + tid];
        float v1 = x[(size_t)r * HC + 256 + tid];
        s0 += v0; q0 += v0 * v0;
        s1 += v1; q1 += v1 * v1;
    }
    atomicAdd(&stats[tid], s0);
    atomicAdd(&stats[HC + tid], q0);
    atomicAdd(&stats[256 + tid], s1);
    atomicAdd(&stats[HC + 256 + tid], q1);
}

__global__ __launch_bounds__(256) void bnapply_kernel(float* __restrict__ x,
                                                      const float* __restrict__ stats,
                                                      const float* __restrict__ g,
                                                      const float* __restrict__ bt,
                                                      __hip_bfloat16* __restrict__ hi,
                                                      __hip_bfloat16* __restrict__ lo,
                                                      int total, float invN) {
    for (int i = blockIdx.x * 256 + threadIdx.x; i < total; i += gridDim.x * 256) {
        int c = i & (HC - 1);
        float mu = stats[c] * invN;
        float var = stats[HC + c] * invN - mu * mu;
        float v = (x[i] - mu) * rsqrtf(var + EPS_BN) * g[c] + bt[c];
        x[i] = v;
        __hip_bfloat16 h = __float2bfloat16(v);
        hi[i] = h;
        lo[i] = __float2bfloat16(v - __bfloat162float(h));
    }
}

// ---------------------------------------------------------------------------
// Head: logits = x[N,64] @ w[64,10] + b; out = log_softmax.  One wave per row.
// ---------------------------------------------------------------------------
__global__ __launch_bounds__(256) void head_kernel(const float* __restrict__ x,
                                                   const float* __restrict__ w,
                                                   const float* __restrict__ b,
                                                   float* __restrict__ out, int N) {
    int wid = (blockIdx.x * 256 + threadIdx.x) >> 6;
    int lane = threadIdx.x & 63;
    if (wid >= N) return;
    float v = x[(size_t)wid * 64 + lane];
    float my = -INFINITY;
#pragma unroll
    for (int j = 0; j < 10; ++j) {
        float t = v * w[lane * 10 + j];
#pragma unroll
        for (int off = 32; off; off >>= 1) t += __shfl_xor(t, off);
        t += b[j];
        if (lane == j) my = t;
    }
    float mx = my;
#pragma unroll
    for (int off = 32; off; off >>= 1) mx = fmaxf(mx, __shfl_xor(mx, off));
    float p = (lane < 10) ? expf(my - mx) : 0.f;
    float sum = p;
#pragma unroll
    for (int off = 32; off; off >>= 1) sum += __shfl_xor(sum, off);
    if (lane < 10) out[(size_t)wid * 10 + lane] = my - mx - logf(sum);
}

// ---------------------------------------------------------------------------
extern "C" void kernel_launch(void* const* d_in, const int* in_sizes, int n_in,
                              void* d_out, int out_size, void* d_ws, size_t ws_size,
                              hipStream_t stream) {
    const float* x = (const float*)d_in[0];
    const int* ei = (const int*)d_in[1];        // [2, E] int32
    const int N = in_sizes[0] / 128;
    const int E = in_sizes[1] / 2;
    const int EN = E + N;

    // ---- workspace layout ----
    float* bufH = (float*)d_ws;                            // N*512  (GEMM out / h)
    float* OUTb = bufH + (size_t)N * HC;                   // N*512  (layer out)
    float* als  = OUTb + (size_t)N * HC;                   // N*4
    float* ald  = als + (size_t)N * NHEAD;                 // N*4
    float* stats = ald + (size_t)N * NHEAD;                // 1024
    __hip_bfloat16* xhi = (__hip_bfloat16*)(stats + 1024); // N*512 bf16
    __hip_bfloat16* xlo = xhi + (size_t)N * HC;            // N*512 bf16
    __hip_bfloat16* wpool = xlo + (size_t)N * HC;
    // weight pool: L1 hi/lo (512*128 each), L2-4 hi/lo (512*512 each)
    __hip_bfloat16* wthi[4], * wtlo[4];
    {
        __hip_bfloat16* p = wpool;
        wthi[0] = p; p += 512 * 128;
        wtlo[0] = p; p += 512 * 128;
        for (int L = 1; L < 4; ++L) {
            wthi[L] = p; p += 512 * 512;
            wtlo[L] = p; p += 512 * 512;
        }
        int* ip = (int*)p;
        // CSR arrays follow
        (void)ip;
    }
    int* rowptr = (int*)(wpool + 2 * 512 * 128 + 6 * 512 * 512);  // N+1
    int* wr = rowptr + (N + 1);                                    // N
    int* eidb = wr + N;                                            // E+N

    // ---- CSR build (once) ----
    hipMemsetAsync(rowptr, 0, (N + 1) * sizeof(int), stream);
    hist_kernel<<<(EN + 255) / 256, 256, 0, stream>>>(ei + E, rowptr, E, N);
    scan_kernel<<<1, 1024, 0, stream>>>(rowptr, wr, N);
    scatter_kernel<<<(EN + 255) / 256, 256, 0, stream>>>(ei + E, wr, eidb, E, N);

    // ---- weight transpose+split (once) ----
    for (int L = 0; L < 4; ++L) {
        const float* W = (const float*)d_in[3 + 6 * L];
        int K = (L == 0) ? 128 : 512;
        wsplit_kernel<<<dim3(512 / 32, K / 32), 256, 0, stream>>>(W, wthi[L], wtlo[L], K, 512);
    }
    // layer-1 input split
    xsplit_kernel<<<1024, 256, 0, stream>>>(x, xhi, xlo, N * 128);

    const int nodeBlocks = (N * 64 + 255) / 256;
    int curK = 128;

    for (int L = 0; L < 4; ++L) {
        const float* as_ = (const float*)d_in[4 + 6 * L];
        const float* ad_ = (const float*)d_in[5 + 6 * L];
        const float* b_  = (const float*)d_in[6 + 6 * L];
        const float* g_  = (const float*)d_in[7 + 6 * L];
        const float* bt_ = (const float*)d_in[8 + 6 * L];

        mfma_gemm<<<dim3(HC / 128, (N + 127) / 128), 256, 0, stream>>>(
            xhi, xlo, wthi[L], wtlo[L], bufH, N, curK, HC);
        al_kernel<<<nodeBlocks, 256, 0, stream>>>(bufH, as_, ad_, als, ald, N);
        agg_kernel<<<nodeBlocks, 256, 0, stream>>>(bufH, als, ald, rowptr, eidb, ei,
                                                   b_, OUTb, N, E);
        hipMemsetAsync(stats, 0, 1024 * sizeof(float), stream);
        bnstat_kernel<<<256, 256, 0, stream>>>(OUTb, stats, N);
        bnapply_kernel<<<2048, 256, 0, stream>>>(OUTb, stats, g_, bt_, xhi, xlo,
                                                 N * HC, 1.f / (float)N);
        curK = HC;
    }

    // ---- MLP head (fp32) ----
    const float* lw1 = (const float*)d_in[27];
    const float* lb1 = (const float*)d_in[28];
    const float* lw2 = (const float*)d_in[29];
    const float* lb2 = (const float*)d_in[30];
    const float* lw3 = (const float*)d_in[31];
    const float* lb3 = (const float*)d_in[32];

    float* m1 = bufH;                        // N*128 (bufH free now)
    float* m2 = bufH + (size_t)N * 128;      // N*64

    gemm_k<64, 64, 16, 4, 4, 1><<<dim3(128 / 64, (N + 63) / 64), 256, 0, stream>>>(
        OUTb, lw1, lb1, m1, N, HC, 128);
    gemm_k<64, 64, 16, 4, 4, 1><<<dim3(1, (N + 63) / 64), 256, 0, stream>>>(
        m1, lw2, lb2, m2, N, 128, 64);
    head_kernel<<<nodeBlocks, 256, 0, stream>>>(m2, lw3, lb3, (float*)d_out, N);
}

// Round 4
// 986.107 us; speedup vs baseline: 1.4624x; 1.1596x over previous
//
#include <hip/hip_runtime.h>
#include <hip/hip_bf16.h>
#include <math.h>

#define HC 512
#define NHEAD 4
#define NEG_SLOPE 0.2f
#define EPS_BN 1e-5f

typedef __attribute__((ext_vector_type(8))) short short8v;      // 8 bf16
typedef __attribute__((ext_vector_type(4))) float f32x4;
typedef _Float16 half8 __attribute__((ext_vector_type(8)));     // 8 fp16 = 16B

#define GLOAD16(gptr, lptr)                                                      \
    __builtin_amdgcn_global_load_lds(                                            \
        (const __attribute__((address_space(1))) unsigned int*)(gptr),           \
        (__attribute__((address_space(3))) unsigned int*)(lptr), 16, 0, 0)

// ---------------------------------------------------------------------------
// CSR build: histogram -> scan -> scatter.  Self-loop ids j in [E,E+N).
// ---------------------------------------------------------------------------
__global__ void hist_kernel(const int* __restrict__ dstE, int* __restrict__ cnt,
                            int E, int N) {
    int i = blockIdx.x * 256 + threadIdx.x;
    if (i < E + N) {
        int d = (i < E) ? dstE[i] : (i - E);
        atomicAdd(&cnt[d], 1);
    }
}

__global__ __launch_bounds__(1024) void scan_kernel(int* __restrict__ rowptr,
                                                    int* __restrict__ wr, int n) {
    __shared__ int sm[1024];
    __shared__ int carry;
    int t = threadIdx.x;
    if (t == 0) carry = 0;
    __syncthreads();
    for (int base = 0; base < n; base += 1024) {
        int v = (base + t < n) ? rowptr[base + t] : 0;
        sm[t] = v;
        __syncthreads();
        for (int off = 1; off < 1024; off <<= 1) {
            int add = (t >= off) ? sm[t - off] : 0;
            __syncthreads();
            sm[t] += add;
            __syncthreads();
        }
        int total = sm[1023];
        int excl = sm[t] - v + carry;
        if (base + t < n) { rowptr[base + t] = excl; wr[base + t] = excl; }
        __syncthreads();
        if (t == 0) carry += total;
        __syncthreads();
    }
    if (t == 0) rowptr[n] = carry;
}

__global__ void scatter_kernel(const int* __restrict__ dstE, int* __restrict__ wr,
                               int* __restrict__ eid, int E, int N) {
    int i = blockIdx.x * 256 + threadIdx.x;
    if (i < E + N) {
        int d = (i < E) ? dstE[i] : (i - E);
        int p = atomicAdd(&wr[d], 1);
        eid[p] = i;
    }
}

// ---------------------------------------------------------------------------
// Weight transpose + hi/lo bf16 split:  W fp32 [K][Nc] -> WT{hi,lo} [Nc][K].
// ---------------------------------------------------------------------------
__global__ __launch_bounds__(256) void wsplit_kernel(const float* __restrict__ W,
                                                     __hip_bfloat16* __restrict__ hiT,
                                                     __hip_bfloat16* __restrict__ loT,
                                                     int K, int Nc) {
    __shared__ float tile[32][33];
    int bx = blockIdx.x * 32;   // n
    int by = blockIdx.y * 32;   // k
    int tx = threadIdx.x & 31, ty = threadIdx.x >> 5;   // 32 x 8
#pragma unroll
    for (int r = 0; r < 32; r += 8)
        tile[ty + r][tx] = W[(size_t)(by + ty + r) * Nc + bx + tx];
    __syncthreads();
#pragma unroll
    for (int r = 0; r < 32; r += 8) {
        int n = bx + ty + r;
        int k = by + tx;
        float w = tile[tx][ty + r];        // tile[kk][nn]: kk=tx, nn=ty+r
        __hip_bfloat16 h = __float2bfloat16(w);
        hiT[(size_t)n * K + k] = h;
        loT[(size_t)n * K + k] = __float2bfloat16(w - __bfloat162float(h));
    }
}

__global__ __launch_bounds__(256) void xsplit_kernel(const float* __restrict__ x,
                                                     __hip_bfloat16* __restrict__ hi,
                                                     __hip_bfloat16* __restrict__ lo,
                                                     int total) {
    for (int i = blockIdx.x * 256 + threadIdx.x; i < total; i += gridDim.x * 256) {
        float v = x[i];
        __hip_bfloat16 h = __float2bfloat16(v);
        hi[i] = h;
        lo[i] = __float2bfloat16(v - __bfloat162float(h));
    }
}

// ---------------------------------------------------------------------------
// bf16 split-GEMM, 128x128 tile, BK=32, 2x2 waves, 16x16x32 MFMA, 3 products.
// EPI 0: store fp16 only (layer h).  EPI 1: +bias, ReLU, store fp32 (MLP).
// ---------------------------------------------------------------------------
template <int EPI>
__global__ __launch_bounds__(256) void mfma_gemm(const __hip_bfloat16* __restrict__ Ahi,
                                                 const __hip_bfloat16* __restrict__ Alo,
                                                 const __hip_bfloat16* __restrict__ BThi,
                                                 const __hip_bfloat16* __restrict__ BTlo,
                                                 float* __restrict__ C,
                                                 _Float16* __restrict__ H16,
                                                 const float* __restrict__ bias,
                                                 int M, int K, int Nc) {
    __shared__ short sm[4 * 128 * 32];          // 32 KiB: Ahi | Alo | Bhi | Blo
    short* sAhi = sm;
    short* sAlo = sm + 4096;
    short* sBhi = sm + 8192;
    short* sBlo = sm + 12288;

    const int tid = threadIdx.x;
    const int wid = tid >> 6, lane = tid & 63;
    const int wm = wid >> 1, wn = wid & 1;      // wave grid 2x2, each 64x64
    const int bm = blockIdx.y * 128, bn = blockIdx.x * 128;

    const int rowl = lane >> 2;
    const int cole = (lane & 3) * 8;
    const int c0 = wid * 2;

    const int frow = lane & 15;
    const int fko = (lane >> 4) * 8;

    f32x4 acc[4][4] = {};

    for (int k0 = 0; k0 < K; k0 += 32) {
#pragma unroll
        for (int cc = 0; cc < 2; ++cc) {
            int c = c0 + cc;
            int ra = bm + c * 16 + rowl; if (ra >= M) ra = M - 1;
            int rb = bn + c * 16 + rowl;
            GLOAD16(Ahi + (size_t)ra * K + k0 + cole, &sAhi[c * 512]);
            GLOAD16(Alo + (size_t)ra * K + k0 + cole, &sAlo[c * 512]);
            GLOAD16(BThi + (size_t)rb * K + k0 + cole, &sBhi[c * 512]);
            GLOAD16(BTlo + (size_t)rb * K + k0 + cole, &sBlo[c * 512]);
        }
        __syncthreads();

        short8v ah[4], al_[4], bh[4], bl[4];
#pragma unroll
        for (int mi = 0; mi < 4; ++mi) {
            int r = wm * 64 + mi * 16 + frow;
            ah[mi] = *(const short8v*)&sAhi[r * 32 + fko];
            al_[mi] = *(const short8v*)&sAlo[r * 32 + fko];
        }
#pragma unroll
        for (int ni = 0; ni < 4; ++ni) {
            int r = wn * 64 + ni * 16 + frow;
            bh[ni] = *(const short8v*)&sBhi[r * 32 + fko];
            bl[ni] = *(const short8v*)&sBlo[r * 32 + fko];
        }
#pragma unroll
        for (int mi = 0; mi < 4; ++mi)
#pragma unroll
            for (int ni = 0; ni < 4; ++ni) {
                acc[mi][ni] = __builtin_amdgcn_mfma_f32_16x16x32_bf16(ah[mi], bh[ni], acc[mi][ni], 0, 0, 0);
                acc[mi][ni] = __builtin_amdgcn_mfma_f32_16x16x32_bf16(ah[mi], bl[ni], acc[mi][ni], 0, 0, 0);
                acc[mi][ni] = __builtin_amdgcn_mfma_f32_16x16x32_bf16(al_[mi], bh[ni], acc[mi][ni], 0, 0, 0);
            }
        __syncthreads();
    }

    // C/D layout: col = lane&15, row = (lane>>4)*4 + reg
    const int crow = (lane >> 4) * 4;
    const int ccol = lane & 15;
#pragma unroll
    for (int mi = 0; mi < 4; ++mi)
#pragma unroll
        for (int ni = 0; ni < 4; ++ni) {
            int gc = bn + wn * 64 + ni * 16 + ccol;
#pragma unroll
            for (int r = 0; r < 4; ++r) {
                int gr = bm + wm * 64 + mi * 16 + crow + r;
                if (gr >= M) continue;
                if (EPI == 0) {
                    H16[(size_t)gr * Nc + gc] = (_Float16)acc[mi][ni][r];
                } else {
                    float v = acc[mi][ni][r] + bias[gc];
                    C[(size_t)gr * Nc + gc] = fmaxf(v, 0.f);
                }
            }
        }
}

// ---------------------------------------------------------------------------
// Tiled fp32 GEMM (small MLP layer 2).  EPI 1 = +bias, ReLU.
// ---------------------------------------------------------------------------
template <int BM, int BN, int BK, int TM, int TN, int EPI>
__global__ __launch_bounds__(256) void gemm_k(const float* __restrict__ A,
                                              const float* __restrict__ B,
                                              const float* __restrict__ bias,
                                              float* __restrict__ C,
                                              int M, int K, int N) {
    constexpr int PAD = 4;
    __shared__ float sA[BK][BM + PAD];
    __shared__ float sB[BK][BN];

    const int tid = threadIdx.x;
    const int bm = blockIdx.y * BM, bn = blockIdx.x * BN;
    constexpr int TX = BN / TN;
    const int tx = tid % TX, ty = tid / TX;

    float acc[TM][TN] = {};

    constexpr int AF4 = BK / 4;
    const int a4 = tid % AF4;
    const int ar0 = tid / AF4;
    constexpr int AROWS = 256 / AF4;
    constexpr int APASS = BM / AROWS;

    constexpr int BF4 = BN / 4;
    const int b4 = tid % BF4;
    const int br0 = tid / BF4;
    constexpr int BROWS = 256 / BF4;
    constexpr int BPASS = BK / BROWS;

    for (int kt = 0; kt < K; kt += BK) {
        __syncthreads();
#pragma unroll
        for (int p = 0; p < APASS; ++p) {
            int row = ar0 + p * AROWS;
            int gr = bm + row;
            if (gr >= M) gr = M - 1;
            float4 v = *(const float4*)&A[(size_t)gr * K + kt + a4 * 4];
            sA[a4 * 4 + 0][row] = v.x;
            sA[a4 * 4 + 1][row] = v.y;
            sA[a4 * 4 + 2][row] = v.z;
            sA[a4 * 4 + 3][row] = v.w;
        }
#pragma unroll
        for (int p = 0; p < BPASS; ++p) {
            int row = br0 + p * BROWS;
            float4 v = *(const float4*)&B[(size_t)(kt + row) * N + bn + b4 * 4];
            *(float4*)&sB[row][b4 * 4] = v;
        }
        __syncthreads();
#pragma unroll
        for (int k = 0; k < BK; ++k) {
            float ar[TM], br[TN];
#pragma unroll
            for (int i = 0; i < TM; i += 4)
                *(float4*)&ar[i] = *(const float4*)&sA[k][ty * TM + i];
#pragma unroll
            for (int j = 0; j < TN; j += 4)
                *(float4*)&br[j] = *(const float4*)&sB[k][tx * TN + j];
#pragma unroll
            for (int i = 0; i < TM; ++i)
#pragma unroll
                for (int j = 0; j < TN; ++j)
                    acc[i][j] = fmaf(ar[i], br[j], acc[i][j]);
        }
    }

#pragma unroll
    for (int i = 0; i < TM; ++i) {
        int r = bm + ty * TM + i;
        if (r >= M) continue;
#pragma unroll
        for (int j = 0; j < TN; j += 4) {
            int c = bn + tx * TN + j;
            float4 v;
            v.x = acc[i][j + 0]; v.y = acc[i][j + 1];
            v.z = acc[i][j + 2]; v.w = acc[i][j + 3];
            if (EPI == 1) {
                v.x = fmaxf(v.x + bias[c + 0], 0.f);
                v.y = fmaxf(v.y + bias[c + 1], 0.f);
                v.z = fmaxf(v.z + bias[c + 2], 0.f);
                v.w = fmaxf(v.w + bias[c + 3], 0.f);
            }
            *(float4*)&C[(size_t)r * N + c] = v;
        }
    }
}

// ---------------------------------------------------------------------------
// Attention coefficients from fp16 h.  One wave per node; lane owns 8
// contiguous channels (all in head lane>>4).
// ---------------------------------------------------------------------------
__global__ __launch_bounds__(256) void al_kernel(const _Float16* __restrict__ h16,
                                                 const float* __restrict__ asrc,
                                                 const float* __restrict__ adst,
                                                 float* __restrict__ al_s,
                                                 float* __restrict__ al_d, int N) {
    int wid = (blockIdx.x * 256 + threadIdx.x) >> 6;
    int lane = threadIdx.x & 63;
    if (wid >= N) return;
    half8 hv = *(const half8*)(h16 + (size_t)wid * HC + lane * 8);
    float ss = 0.f, sd = 0.f;
#pragma unroll
    for (int j = 0; j < 8; ++j) {
        float v = (float)hv[j];
        ss = fmaf(v, asrc[lane * 8 + j], ss);
        sd = fmaf(v, adst[lane * 8 + j], sd);
    }
#pragma unroll
    for (int off = 8; off; off >>= 1) {     // reduce within 16-lane head group
        ss += __shfl_xor(ss, off);
        sd += __shfl_xor(sd, off);
    }
    if ((lane & 15) == 0) {
        al_s[wid * NHEAD + (lane >> 4)] = ss;
        al_d[wid * NHEAD + (lane >> 4)] = sd;
    }
}

// ---------------------------------------------------------------------------
// Aggregation: one wave per dst node.  Phases: per-head max -> sum of exp ->
// fp16 weighted gather (lane owns 8 contiguous channels).  +bias, ELU.
// ---------------------------------------------------------------------------
__global__ __launch_bounds__(256) void agg_kernel(const _Float16* __restrict__ h16,
                                                  const float* __restrict__ al_s,
                                                  const float* __restrict__ al_d,
                                                  const int* __restrict__ rowptr,
                                                  const int* __restrict__ eid,
                                                  const int* __restrict__ srcE,
                                                  const float* __restrict__ bias,
                                                  float* __restrict__ out,
                                                  int N, int E) {
    int node = (blockIdx.x * 256 + threadIdx.x) >> 6;
    int lane = threadIdx.x & 63;
    if (node >= N) return;
    int e0 = rowptr[node], e1 = rowptr[node + 1];
    float4 ald4 = *(const float4*)&al_d[node * NHEAD];
    float aldv[NHEAD] = {ald4.x, ald4.y, ald4.z, ald4.w};

    // phase 1: per-head max of leaky_relu logits
    float m[NHEAD] = {-INFINITY, -INFINITY, -INFINITY, -INFINITY};
    for (int i = e0 + lane; i < e1; i += 64) {
        int j = eid[i];
        int src = (j < E) ? srcE[j] : node;
        float4 als4 = *(const float4*)&al_s[src * NHEAD];
        float alsv[NHEAD] = {als4.x, als4.y, als4.z, als4.w};
#pragma unroll
        for (int h = 0; h < NHEAD; ++h) {
            float e = alsv[h] + aldv[h];
            e = (e > 0.f) ? e : NEG_SLOPE * e;
            m[h] = fmaxf(m[h], e);
        }
    }
#pragma unroll
    for (int off = 32; off; off >>= 1)
#pragma unroll
        for (int h = 0; h < NHEAD; ++h) m[h] = fmaxf(m[h], __shfl_xor(m[h], off));

    // phase 2: sum of exp
    float s[NHEAD] = {0, 0, 0, 0};
    for (int i = e0 + lane; i < e1; i += 64) {
        int j = eid[i];
        int src = (j < E) ? srcE[j] : node;
        float4 als4 = *(const float4*)&al_s[src * NHEAD];
        float alsv[NHEAD] = {als4.x, als4.y, als4.z, als4.w};
#pragma unroll
        for (int h = 0; h < NHEAD; ++h) {
            float e = alsv[h] + aldv[h];
            e = (e > 0.f) ? e : NEG_SLOPE * e;
            s[h] += __expf(e - m[h]);
        }
    }
#pragma unroll
    for (int off = 32; off; off >>= 1)
#pragma unroll
        for (int h = 0; h < NHEAD; ++h) s[h] += __shfl_xor(s[h], off);

    // per-lane head (channels 8*lane .. 8*lane+7 all in head lane>>4)
    int hl = lane >> 4;
    float ald_l = (hl < 2) ? (hl == 0 ? aldv[0] : aldv[1]) : (hl == 2 ? aldv[2] : aldv[3]);
    float m_l   = (hl < 2) ? (hl == 0 ? m[0] : m[1]) : (hl == 2 ? m[2] : m[3]);
    float s_l   = (hl < 2) ? (hl == 0 ? s[0] : s[1]) : (hl == 2 ? s[2] : s[3]);
    float rs_l = 1.f / (s_l + 1e-16f);

    // phase 3: fp16 weighted gather
    float acc[8] = {0, 0, 0, 0, 0, 0, 0, 0};
    for (int i = e0; i < e1; ++i) {
        int j = eid[i];
        int src = (j < E) ? srcE[j] : node;
        float4 als4 = *(const float4*)&al_s[src * NHEAD];
        float as_l = (hl < 2) ? (hl == 0 ? als4.x : als4.y) : (hl == 2 ? als4.z : als4.w);
        float e = as_l + ald_l;
        e = (e > 0.f) ? e : NEG_SLOPE * e;
        float w = __expf(e - m_l) * rs_l;
        half8 hv = *(const half8*)(h16 + (size_t)src * HC + lane * 8);
#pragma unroll
        for (int k = 0; k < 8; ++k)
            acc[k] = fmaf((float)hv[k], w, acc[k]);
    }

#pragma unroll
    for (int k = 0; k < 8; ++k) {
        float v = acc[k] + bias[lane * 8 + k];
        acc[k] = (v > 0.f) ? v : (__expf(v) - 1.f);
    }
    float4* op = (float4*)(out + (size_t)node * HC + lane * 8);
    op[0] = make_float4(acc[0], acc[1], acc[2], acc[3]);
    op[1] = make_float4(acc[4], acc[5], acc[6], acc[7]);
}

// ---------------------------------------------------------------------------
// BatchNorm stats in DOUBLE (order-stable to ~1e-12 -> replay-deterministic
// output) + apply (emits hi/lo bf16 for the next GEMM).
// ---------------------------------------------------------------------------
__global__ __launch_bounds__(256) void bnstat_kernel(const float* __restrict__ x,
                                                     double* __restrict__ stats, int N) {
    int tid = threadIdx.x;
    double s0 = 0, s1 = 0, q0 = 0, q1 = 0;
    for (int r = blockIdx.x; r < N; r += gridDim.x) {
        double v0 = (double)x[(size_t)r * HC + tid];
        double v1 = (double)x[(size_t)r * HC + 256 + tid];
        s0 += v0; q0 += v0 * v0;
        s1 += v1; q1 += v1 * v1;
    }
    atomicAdd(&stats[tid], s0);
    atomicAdd(&stats[HC + tid], q0);
    atomicAdd(&stats[256 + tid], s1);
    atomicAdd(&stats[HC + 256 + tid], q1);
}

__global__ __launch_bounds__(256) void bnapply_kernel(float* __restrict__ x,
                                                      const double* __restrict__ stats,
                                                      const float* __restrict__ g,
                                                      const float* __restrict__ bt,
                                                      __hip_bfloat16* __restrict__ hi,
                                                      __hip_bfloat16* __restrict__ lo,
                                                      int total, double invN) {
    for (int i = blockIdx.x * 256 + threadIdx.x; i < total; i += gridDim.x * 256) {
        int c = i & (HC - 1);
        double mu = stats[c] * invN;
        double var = stats[HC + c] * invN - mu * mu;
        float scale = (float)rsqrt(var + (double)EPS_BN);
        float v = ((x[i] - (float)mu) * scale) * g[c] + bt[c];
        x[i] = v;
        __hip_bfloat16 h = __float2bfloat16(v);
        hi[i] = h;
        lo[i] = __float2bfloat16(v - __bfloat162float(h));
    }
}

// ---------------------------------------------------------------------------
// Head: logits = x[N,64] @ w[64,10] + b; log_softmax.  One wave per row.
// ---------------------------------------------------------------------------
__global__ __launch_bounds__(256) void head_kernel(const float* __restrict__ x,
                                                   const float* __restrict__ w,
                                                   const float* __restrict__ b,
                                                   float* __restrict__ out, int N) {
    int wid = (blockIdx.x * 256 + threadIdx.x) >> 6;
    int lane = threadIdx.x & 63;
    if (wid >= N) return;
    float v = x[(size_t)wid * 64 + lane];
    float my = -INFINITY;
#pragma unroll
    for (int j = 0; j < 10; ++j) {
        float t = v * w[lane * 10 + j];
#pragma unroll
        for (int off = 32; off; off >>= 1) t += __shfl_xor(t, off);
        t += b[j];
        if (lane == j) my = t;
    }
    float mx = my;
#pragma unroll
    for (int off = 32; off; off >>= 1) mx = fmaxf(mx, __shfl_xor(mx, off));
    float p = (lane < 10) ? expf(my - mx) : 0.f;
    float sum = p;
#pragma unroll
    for (int off = 32; off; off >>= 1) sum += __shfl_xor(sum, off);
    if (lane < 10) out[(size_t)wid * 10 + lane] = my - mx - logf(sum);
}

// ---------------------------------------------------------------------------
extern "C" void kernel_launch(void* const* d_in, const int* in_sizes, int n_in,
                              void* d_out, int out_size, void* d_ws, size_t ws_size,
                              hipStream_t stream) {
    const float* x = (const float*)d_in[0];
    const int* ei = (const int*)d_in[1];        // [2, E] int32
    const int N = in_sizes[0] / 128;
    const int E = in_sizes[1] / 2;
    const int EN = E + N;

    // ---- workspace layout ----
    float* OUTb = (float*)d_ws;                            // N*512 (layer out)
    float* als  = OUTb + (size_t)N * HC;                   // N*4
    float* ald  = als + (size_t)N * NHEAD;                 // N*4
    double* stats = (double*)(ald + (size_t)N * NHEAD);    // 1024 doubles
    float* m1 = (float*)(stats + 1024);                    // N*128
    float* m2 = m1 + (size_t)N * 128;                      // N*64
    _Float16* h16 = (_Float16*)(m2 + (size_t)N * 64);      // N*512 fp16
    __hip_bfloat16* xhi = (__hip_bfloat16*)(h16 + (size_t)N * HC);  // N*512
    __hip_bfloat16* xlo = xhi + (size_t)N * HC;            // N*512
    __hip_bfloat16* wpool = xlo + (size_t)N * HC;
    __hip_bfloat16* wthi[4], * wtlo[4], * mlphi, * mlplo;
    {
        __hip_bfloat16* p = wpool;
        wthi[0] = p; p += 512 * 128;
        wtlo[0] = p; p += 512 * 128;
        for (int L = 1; L < 4; ++L) {
            wthi[L] = p; p += 512 * 512;
            wtlo[L] = p; p += 512 * 512;
        }
        mlphi = p; p += 128 * 512;
        mlplo = p; p += 128 * 512;
    }
    int* rowptr = (int*)(wpool + 2 * 512 * 128 + 6 * 512 * 512 + 2 * 128 * 512);
    int* wr = rowptr + (N + 1);
    int* eidb = wr + N;

    // ---- CSR build (once) ----
    hipMemsetAsync(rowptr, 0, (N + 1) * sizeof(int), stream);
    hist_kernel<<<(EN + 255) / 256, 256, 0, stream>>>(ei + E, rowptr, E, N);
    scan_kernel<<<1, 1024, 0, stream>>>(rowptr, wr, N);
    scatter_kernel<<<(EN + 255) / 256, 256, 0, stream>>>(ei + E, wr, eidb, E, N);

    // ---- weight transpose+split (once) ----
    for (int L = 0; L < 4; ++L) {
        const float* W = (const float*)d_in[3 + 6 * L];
        int K = (L == 0) ? 128 : 512;
        wsplit_kernel<<<dim3(512 / 32, K / 32), 256, 0, stream>>>(W, wthi[L], wtlo[L], K, 512);
    }
    wsplit_kernel<<<dim3(128 / 32, 512 / 32), 256, 0, stream>>>(
        (const float*)d_in[27], mlphi, mlplo, 512, 128);
    xsplit_kernel<<<1024, 256, 0, stream>>>(x, xhi, xlo, N * 128);

    const int nodeBlocks = (N * 64 + 255) / 256;
    int curK = 128;

    for (int L = 0; L < 4; ++L) {
        const float* as_ = (const float*)d_in[4 + 6 * L];
        const float* ad_ = (const float*)d_in[5 + 6 * L];
        const float* b_  = (const float*)d_in[6 + 6 * L];
        const float* g_  = (const float*)d_in[7 + 6 * L];
        const float* bt_ = (const float*)d_in[8 + 6 * L];

        mfma_gemm<0><<<dim3(HC / 128, (N + 127) / 128), 256, 0, stream>>>(
            xhi, xlo, wthi[L], wtlo[L], nullptr, h16, nullptr, N, curK, HC);
        al_kernel<<<nodeBlocks, 256, 0, stream>>>(h16, as_, ad_, als, ald, N);
        agg_kernel<<<nodeBlocks, 256, 0, stream>>>(h16, als, ald, rowptr, eidb, ei,
                                                   b_, OUTb, N, E);
        hipMemsetAsync(stats, 0, 1024 * sizeof(double), stream);
        bnstat_kernel<<<256, 256, 0, stream>>>(OUTb, stats, N);
        bnapply_kernel<<<2048, 256, 0, stream>>>(OUTb, stats, g_, bt_, xhi, xlo,
                                                 N * HC, 1.0 / (double)N);
        curK = HC;
    }

    // ---- MLP head ----
    const float* lb1 = (const float*)d_in[28];
    const float* lw2 = (const float*)d_in[29];
    const float* lb2 = (const float*)d_in[30];
    const float* lw3 = (const float*)d_in[31];
    const float* lb3 = (const float*)d_in[32];

    mfma_gemm<1><<<dim3(1, (N + 127) / 128), 256, 0, stream>>>(
        xhi, xlo, mlphi, mlplo, m1, nullptr, lb1, N, HC, 128);
    gemm_k<64, 64, 16, 4, 4, 1><<<dim3(1, (N + 63) / 64), 256, 0, stream>>>(
        m1, lw2, lb2, m2, N, 128, 64);
    head_kernel<<<nodeBlocks, 256, 0, stream>>>(m2, lw3, lb3, (float*)d_out, N);
}